// Round 5
// baseline (424.709 us; speedup 1.0000x reference)
//
#include <hip/hip_runtime.h>
#include <cmath>

// GHM-C two-stage loss, single data pass.
// loss = (1/N) * sum_b beta_b * sum_ce[b],  beta_b = 1/clip(cnt_b*nonempty, 1e-4)
//
// R5: register-prefetch double buffer. R4 (~115us main) was latency-exposed:
// per tile, serial load->vmcnt(0)->LDS->compute with only ~2 waves/SIMD to
// cover ~900cyc HBM latency. Now tile k+1's 16 global loads are issued right
// after tile k's LDS write and fly during tile k's compute. STRIDE 66->68
// makes all LDS rows 16B-aligned for every thread -> b128 reads/writes,
// conflict-free (float4-bank-group = (t+e) mod 8). Grid 2304 = 9 blocks/CU
// (17.4KB LDS each).

#define BINS 10
#define MAIN_BLOCKS 2304
#define STRIDE 68            // floats per LDS row = 17 float4, 16B-aligned rows

__global__ __launch_bounds__(64) void ghmc_main_kernel(
    const float* __restrict__ x,
    const int* __restrict__ target,
    const float* __restrict__ weight,
    const int* __restrict__ stage_p,
    double* __restrict__ part_ce,        // [BINS * MAIN_BLOCKS], bin-major
    unsigned int* __restrict__ part_cnt, // [BINS * MAIN_BLOCKS]
    int N)
{
    __shared__ float        s_x[64 * STRIDE];   // 17408 B
    __shared__ double       s_ce[BINS];
    __shared__ unsigned int s_cnt[BINS];

    const int tid = threadIdx.x;   // 0..63, ONE wave per block (no barriers)
    if (tid < BINS) { s_ce[tid] = 0.0; s_cnt[tid] = 0u; }

    const int stage = *stage_p;
    const float4* __restrict__ x4 = (const float4*)x;
    const unsigned int ntiles = (unsigned int)N >> 6;   // N % 64 == 0

    unsigned int cnt9 = 0;
    double ce9 = 0.0;

    unsigned int tile = blockIdx.x;
    bool valid = tile < ntiles;

    float4 buf[16];
    if (valid) {
        const size_t tb4 = (size_t)tile << 10;
        #pragma unroll
        for (int j = 0; j < 16; j++)
            buf[j] = x4[tb4 + (unsigned)((j << 6) + tid)];
    }

    while (valid) {
        // ---- commit buffered tile to LDS (b128, conflict-free) ----
        #pragma unroll
        for (int j = 0; j < 16; j++) {
            int i = (j << 6) + tid;              // 0..1023
            int r = i >> 4, c = i & 15;
            ((float4*)&s_x[r * STRIDE])[c] = buf[j];
        }

        // ---- prefetch next tile into registers (flies during compute) ----
        const unsigned int next = tile + MAIN_BLOCKS;
        const bool nvalid = next < ntiles;
        if (nvalid) {
            const size_t nb4 = (size_t)next << 10;
            #pragma unroll
            for (int j = 0; j < 16; j++)
                buf[j] = x4[nb4 + (unsigned)((j << 6) + tid)];
        }

        // ---- compute: thread tid owns row (tile*64+tid) from LDS ----
        const float4* __restrict__ vp = (const float4*)&s_x[tid * STRIDE];

        float4 v[16];
        #pragma unroll
        for (int e = 0; e < 16; e++) v[e] = vp[e];   // 16 ds_read_b128

        float mx[16];
        #pragma unroll
        for (int e = 0; e < 16; e++)
            mx[e] = fmaxf(fmaxf(v[e].x, v[e].y), fmaxf(v[e].z, v[e].w));
        #pragma unroll
        for (int w = 8; w > 0; w >>= 1) {
            #pragma unroll
            for (int e = 0; e < w; e++) mx[e] = fmaxf(mx[e], mx[e + w]);
        }
        const float m = mx[0];

        float sm[16];
        #pragma unroll
        for (int e = 0; e < 16; e++)
            sm[e] = (expf(v[e].x - m) + expf(v[e].y - m))
                  + (expf(v[e].z - m) + expf(v[e].w - m));
        #pragma unroll
        for (int w = 8; w > 0; w >>= 1) {
            #pragma unroll
            for (int e = 0; e < w; e++) sm[e] += sm[e + w];
        }
        const float s = sm[0];

        int   t  = target[tile * 64u + (unsigned)tid];   // coalesced
        float vt = s_x[tid * STRIDE + t];
        // fp32 sequence mirrors the reference
        float log_pt = (vt - m) - logf(s);
        float w  = (stage == 1) ? 1.0f : weight[t];
        float ce = -(w * log_pt);
        float g  = fabsf(expf(log_pt) - 1.0f);
        int b = (int)floorf(g * 9.9999f);     // BINS - EPS_BIN in fp32
        b = b < 0 ? 0 : (b > 9 ? 9 : b);
        if (b == 9) {
            cnt9++;
            ce9 += (double)ce;
        } else {
            atomicAdd(&s_cnt[b], 1u);         // LDS atomic, rare (~1-3%)
            atomicAdd(&s_ce[b], (double)ce);
        }

        tile = next;
        valid = nvalid;
    }

    // once per block: wave-reduce the dominant bin
    #pragma unroll
    for (int off = 32; off > 0; off >>= 1) {
        cnt9 += __shfl_xor(cnt9, off, 64);
        ce9  += __shfl_xor(ce9, off, 64);
    }
    if (tid == 0) { s_cnt[9] += cnt9; s_ce[9] += ce9; }

    // single-wave block: program order guarantees LDS visibility
    if (tid < BINS) {
        part_ce [tid * MAIN_BLOCKS + blockIdx.x] = s_ce[tid];
        part_cnt[tid * MAIN_BLOCKS + blockIdx.x] = s_cnt[tid];
    }
}

__global__ __launch_bounds__(1024) void ghmc_final_kernel(
    const double* __restrict__ part_ce,
    const unsigned int* __restrict__ part_cnt,
    float* __restrict__ out, int N)
{
    __shared__ double       s_ce[BINS];
    __shared__ unsigned int s_cnt[BINS];
    if (threadIdx.x < BINS) { s_ce[threadIdx.x] = 0.0; s_cnt[threadIdx.x] = 0u; }
    __syncthreads();

    #pragma unroll
    for (int b = 0; b < BINS; b++) {
        double ce = 0.0; unsigned int cnt = 0u;
        for (int k = threadIdx.x; k < MAIN_BLOCKS; k += 1024) {  // coalesced
            ce  += part_ce [b * MAIN_BLOCKS + k];
            cnt += part_cnt[b * MAIN_BLOCKS + k];
        }
        #pragma unroll
        for (int off = 32; off > 0; off >>= 1) {
            ce  += __shfl_xor(ce, off, 64);
            cnt += __shfl_xor(cnt, off, 64);
        }
        if ((threadIdx.x & 63) == 0) {
            atomicAdd(&s_ce[b], ce);
            atomicAdd(&s_cnt[b], cnt);
        }
    }
    __syncthreads();

    if (threadIdx.x == 0) {
        int nonempty = 0;
        #pragma unroll
        for (int b = 0; b < BINS; b++) nonempty += (s_cnt[b] > 0u) ? 1 : 0;
        double total = 0.0;
        #pragma unroll
        for (int b = 0; b < BINS; b++) {
            float gd = (float)s_cnt[b] * (float)nonempty;  // exact ints < 2^24
            gd = fmaxf(gd, 1e-4f);
            total += s_ce[b] / (double)gd;
        }
        out[0] = (float)(total / (double)N);
    }
}

extern "C" void kernel_launch(void* const* d_in, const int* in_sizes, int n_in,
                              void* d_out, int out_size, void* d_ws, size_t ws_size,
                              hipStream_t stream) {
    const float* x       = (const float*)d_in[0];
    const int* target    = (const int*)d_in[1];
    const float* weight  = (const float*)d_in[2];
    const int* stage_p   = (const int*)d_in[3];
    const int N = in_sizes[1];          // rows; C == 64, N % 64 == 0 assumed

    double* part_ce = (double*)d_ws;                       // 180 KiB + 90 KiB
    unsigned int* part_cnt = (unsigned int*)(part_ce + BINS * MAIN_BLOCKS);

    // every partial slot is overwritten by the main kernel -> no memset needed
    ghmc_main_kernel<<<MAIN_BLOCKS, 64, 0, stream>>>(x, target, weight, stage_p,
                                                     part_ce, part_cnt, N);
    ghmc_final_kernel<<<1, 1024, 0, stream>>>(part_ce, part_cnt, (float*)d_out, N);
}